// Round 9
// baseline (732.845 us; speedup 1.0000x reference)
//
#include <hip/hip_runtime.h>

#define NPTS 4096
#define BNROWS 16384

__device__ __forceinline__ float lrelu(float h) { return h > 0.f ? h : 0.2f * h; }

// wave-local LDS fence: orders this wave's LDS ops (lockstep wave64 + lgkmcnt)
#define WSYNC asm volatile("s_waitcnt lgkmcnt(0)" ::: "memory")

__device__ __forceinline__ float rfl(float v) {
  return __int_as_float(__builtin_amdgcn_readfirstlane(__float_as_int(v)));
}

// ========== K0a: transpose x -> xT[b][c][j] + per-row norms ==========
__global__ __launch_bounds__(256) void xpose_kernel(
    const float* __restrict__ x, float* __restrict__ xT, float* __restrict__ sqx)
{
  __shared__ float tile[64][17];
  int t = threadIdx.x;
  int j0 = blockIdx.x * 64;         // global row base
  int b = j0 >> 12;
  int jloc0 = j0 & 4095;
  int p = t >> 2, q = t & 3;
  const float4* xp = (const float4*)(x + (size_t)(j0 + p) * 16);
  float4 v = xp[q];
  tile[p][q*4+0] = v.x; tile[p][q*4+1] = v.y; tile[p][q*4+2] = v.z; tile[p][q*4+3] = v.w;
  __syncthreads();
  int jj = t & 63, chi = t >> 6;
  float* xTb = xT + (size_t)b * 65536;
  #pragma unroll
  for (int i = 0; i < 4; ++i) {
    int c = chi * 4 + i;
    xTb[c * 4096 + jloc0 + jj] = tile[jj][c];
  }
  if (t < 64) {
    float s = 0.f;
    #pragma unroll
    for (int c = 0; c < 16; ++c) { float vv = tile[t][c]; s = fmaf(vv, vv, s); }
    sqx[j0 + t] = s;
  }
}

// ========== K0b: transpose pos -> posT[b][c][j] ==========
__global__ __launch_bounds__(192) void ppose_kernel(
    const float* __restrict__ pos, float* __restrict__ posT)
{
  __shared__ float raw[768];
  int t = threadIdx.x;
  int j0 = blockIdx.x * 256;
  int b = j0 >> 12;
  int jloc0 = j0 & 4095;
  const float4* pp = (const float4*)(pos + (size_t)j0 * 3);
  float4 v = pp[t];
  raw[t*4+0] = v.x; raw[t*4+1] = v.y; raw[t*4+2] = v.z; raw[t*4+3] = v.w;
  __syncthreads();
  float* pTb = posT + (size_t)b * 12288;
  #pragma unroll
  for (int i = 0; i < 4; ++i) {
    int idx = t + 192 * i;          // 0..767
    int c = idx >> 8, jj = idx & 255;
    pTb[c * 4096 + jloc0 + jj] = raw[jj * 3 + c];
  }
}

// ================= K1: pos 128-NN (sorted) + idx_pos ==================
// 8 waves/block, one row per wave, barrier-free; coalesced posT reads.
__global__ __launch_bounds__(512) void knn_pos_kernel(
    const float* __restrict__ pos, const float* __restrict__ posT,
    int* __restrict__ idx_l, int* __restrict__ idx1_i, float* __restrict__ idx1_f)
{
  __shared__ unsigned long long cKey[8][512];
  __shared__ unsigned int cCnt[8];
  int tid = threadIdx.x;
  int w = tid >> 6, lane = tid & 63;
  int r = blockIdx.x * 8 + w;
  int b = r >> 12, n = r & 4095;
  const float* pb = pos + (size_t)b * NPTS * 3;
  const float* pT = posT + (size_t)b * 12288;
  float cx = pb[n*3+0], cy = pb[n*3+1], cz = pb[n*3+2];
  if (lane == 0) cCnt[w] = 0u;
  WSYNC;

  unsigned int qp[32];
  int m1 = 65536, m2 = 65536, m3 = 65536;
  #pragma unroll
  for (int t = 0; t < 32; ++t) {
    unsigned int wq = 0u;
    #pragma unroll
    for (int h = 0; h < 2; ++h) {
      int j = (2*t + h) * 64 + lane;
      float dx = cx - pT[j], dy = cy - pT[4096 + j], dz = cz - pT[8192 + j];
      float d2 = dx*dx + dy*dy + dz*dz;
      int q = (int)(d2 * 1000.0f);
      q = q < 0 ? 0 : (q > 65535 ? 65535 : q);
      wq |= ((unsigned int)q) << (16*h);
      int nm1 = min(m1, q);
      int nm2 = min(m2, max(m1, q));
      int nm3 = min(m3, max(m2, q));
      m1 = nm1; m2 = nm2; m3 = nm3;
    }
    qp[t] = wq;
  }
  // smallest qt with >=43 lanes having 3rd-min <= qt  => >=129 pts <= qt
  int lo = 0, hi = 65535;
  #pragma unroll
  for (int it = 0; it < 16; ++it) {
    int mid = (lo + hi) >> 1;
    int cnt = __popcll(__ballot(m3 <= mid));
    if (cnt >= 43) hi = mid; else lo = mid + 1;
  }
  unsigned int qt = (unsigned int)lo + 2u;   // +2 bucket slack (fp32 vs fp64)

  #pragma unroll
  for (int t = 0; t < 32; ++t) {
    unsigned int wq = qp[t];
    unsigned int q0 = wq & 0xffffu, q1 = wq >> 16;
    if (q0 <= qt) { unsigned int p = atomicAdd(&cCnt[w], 1u); if (p < 512u) cKey[w][p] = (unsigned long long)((2*t)*64 + lane); }
    if (q1 <= qt) { unsigned int p = atomicAdd(&cCnt[w], 1u); if (p < 512u) cKey[w][p] = (unsigned long long)((2*t+1)*64 + lane); }
  }
  WSYNC;
  unsigned int nc = cCnt[w]; if (nc > 512u) nc = 512u;
  int M = (nc <= 256u) ? 256 : 512;
  int EPL = M >> 6;

  // exact fp64 rerank in place -> packed (key|idx), pad with ~0
  double cxd = (double)cx, cyd = (double)cy, czd = (double)cz;
  for (int t = 0; t < EPL; ++t) {
    int c = lane + (t << 6);
    unsigned long long kk = ~0ull;
    if (c < (int)nc) {
      int id = (int)cKey[w][c];
      double dx = cxd - (double)pb[id*3+0];
      double dy = cyd - (double)pb[id*3+1];
      double dz = czd - (double)pb[id*3+2];
      double d2 = dx*dx + dy*dy + dz*dz;
      unsigned long long bits = (unsigned long long)__double_as_longlong(d2);
      kk = (bits & ~0xFFFull) | (unsigned long long)(unsigned int)id;
    }
    cKey[w][c] = kk;
  }
  WSYNC;

  // wave-private bitonic-M on packed keys, ascending
  for (int k = 2; k <= M; k <<= 1) {
    for (int j = k >> 1; j > 0; j >>= 1) {
      for (int t = 0; t < EPL; ++t) {
        int i = lane + (t << 6);
        int ixj = i ^ j;
        if (ixj > i) {
          unsigned long long ka = cKey[w][i], kb = cKey[w][ixj];
          bool up = ((i & k) == 0);
          if ((ka > kb) == up) { cKey[w][i] = kb; cKey[w][ixj] = ka; }
        }
      }
      WSYNC;
    }
  }
  idx_l[(size_t)r * 128 + lane]      = (int)(cKey[w][lane] & 0xFFFull);
  idx_l[(size_t)r * 128 + lane + 64] = (int)(cKey[w][lane + 64] & 0xFFFull);
  if (lane < 6) {
    int v = (int)(cKey[w][1 + lane] & 0xFFFull);
    idx1_i[r * 14 + 8 + lane] = v;
    idx1_f[r * 14 + 8 + lane] = (float)v;
  }
}

// ================= K2: feature 8-NN (excl self), v4 ==================
// 256 threads / 4 rows; SGPR/VGPR centers; coalesced xT reads; fp32 keys in
// registers; float-bit ballot threshold; per-wave fp64 rerank.
__global__ __launch_bounds__(256) void knn_feat_kernel(
    const float* __restrict__ x, const float* __restrict__ xT,
    const float* __restrict__ sqx,
    int* __restrict__ idx1_i, float* __restrict__ idx1_f)
{
  __shared__ float lmin[4][256];
  __shared__ int cand[4][192];
  __shared__ unsigned int cCnt[4];
  __shared__ float qtS[4];
  __shared__ float ctrf[4][16];
  int tid = threadIdx.x;
  int w = tid >> 6, lane = tid & 63;
  int rbase = blockIdx.x * 4;
  int b = rbase >> 12;
  const float* xb  = x  + (size_t)b * NPTS * 16;
  const float* xTb = xT + (size_t)b * 65536;
  const float* sqb = sqx + b * NPTS;

  if (tid < 64) {
    int rr = tid >> 4, c = tid & 15;
    ctrf[rr][c] = xb[(size_t)((rbase + rr) & 4095) * 16 + c];   // batch-local row
  }
  if (tid < 4) cCnt[tid] = 0u;
  __syncthreads();

  // centers: cm = -2*ctr, c2 = |ctr|^2 (wave-uniform)
  float cm[4][16], c2[4];
  #pragma unroll
  for (int rr = 0; rr < 4; ++rr) {
    float s = 0.f;
    #pragma unroll
    for (int c = 0; c < 16; ++c) {
      float v = ctrf[rr][c];
      cm[rr][c] = rfl(-2.0f * v);
      s = fmaf(v, v, s);
    }
    c2[rr] = rfl(s);
  }

  // distance pass: coalesced xT dword loads, fp32 Gram keys in registers
  float key[4][16];
  float fk[4] = {3.4e38f, 3.4e38f, 3.4e38f, 3.4e38f};
  #pragma unroll
  for (int pt = 0; pt < 16; ++pt) {
    int j = tid + 256 * pt;
    float sqj = sqb[j];
    float a0 = sqj + c2[0], a1 = sqj + c2[1], a2 = sqj + c2[2], a3 = sqj + c2[3];
    #pragma unroll
    for (int c = 0; c < 16; ++c) {
      float va = xTb[c * 4096 + j];
      a0 = fmaf(va, cm[0][c], a0);
      a1 = fmaf(va, cm[1][c], a1);
      a2 = fmaf(va, cm[2][c], a2);
      a3 = fmaf(va, cm[3][c], a3);
    }
    key[0][pt] = a0; key[1][pt] = a1; key[2][pt] = a2; key[3][pt] = a3;
    fk[0] = fminf(fk[0], a0); fk[1] = fminf(fk[1], a1);
    fk[2] = fminf(fk[2], a2); fk[3] = fminf(fk[3], a3);
  }
  #pragma unroll
  for (int rr = 0; rr < 4; ++rr) lmin[rr][tid] = fk[rr];
  __syncthreads();

  // wave w: threshold for row w = 10th smallest of 256 thread-minima
  {
    float lv0 = lmin[w][lane], lv1 = lmin[w][lane + 64];
    float lv2 = lmin[w][lane + 128], lv3 = lmin[w][lane + 192];
    unsigned int lo = 0u, hi = 0x7F800000u;
    for (int it = 0; it < 31; ++it) {
      unsigned int mid = (lo + hi) >> 1;
      float midf = __uint_as_float(mid);
      int cnt = __popcll(__ballot(lv0 <= midf)) + __popcll(__ballot(lv1 <= midf))
              + __popcll(__ballot(lv2 <= midf)) + __popcll(__ballot(lv3 <= midf));
      if (cnt >= 10) hi = mid; else lo = mid + 1;
    }
    if (lane == 0) qtS[w] = __uint_as_float(hi) * 1.0002f + 1e-3f;
  }
  __syncthreads();

  // compaction
  {
    float q0 = qtS[0], q1 = qtS[1], q2 = qtS[2], q3 = qtS[3];
    #pragma unroll
    for (int pt = 0; pt < 16; ++pt) {
      int j = tid + 256 * pt;
      if (key[0][pt] <= q0) { unsigned int p = atomicAdd(&cCnt[0], 1u); if (p < 192u) cand[0][p] = j; }
      if (key[1][pt] <= q1) { unsigned int p = atomicAdd(&cCnt[1], 1u); if (p < 192u) cand[1][p] = j; }
      if (key[2][pt] <= q2) { unsigned int p = atomicAdd(&cCnt[2], 1u); if (p < 192u) cand[2][p] = j; }
      if (key[3][pt] <= q3) { unsigned int p = atomicAdd(&cCnt[3], 1u); if (p < 192u) cand[3][p] = j; }
    }
  }
  __syncthreads();

  // wave w: fp64 rerank + 9 sorted min-extractions (rank0 = self, dropped)
  {
    int nc = (int)cCnt[w]; if (nc > 192) nc = 192;
    double key64[3]; int kid[3];
    #pragma unroll
    for (int s = 0; s < 3; ++s) {
      int c = lane + 64*s;
      if (c < nc) {
        int id = cand[w][c];
        const float4* xp = (const float4*)(xb + (size_t)id * 16);
        float4 q0 = xp[0], q1 = xp[1], q2 = xp[2], q3 = xp[3];
        float xv[16] = {q0.x,q0.y,q0.z,q0.w, q1.x,q1.y,q1.z,q1.w,
                        q2.x,q2.y,q2.z,q2.w, q3.x,q3.y,q3.z,q3.w};
        double acc = 0.0;
        #pragma unroll
        for (int c2i = 0; c2i < 16; ++c2i) { double d = (double)ctrf[w][c2i] - (double)xv[c2i]; acc += d * d; }
        key64[s] = acc; kid[s] = id;
      } else { key64[s] = 1e300; kid[s] = 0x7fffffff; }
    }
    int row = rbase + w;
    for (int it = 0; it < 9; ++it) {
      double bk = key64[0]; int bi = kid[0], bs = 0;
      if (key64[1] < bk || (key64[1] == bk && kid[1] < bi)) { bk = key64[1]; bi = kid[1]; bs = 1; }
      if (key64[2] < bk || (key64[2] == bk && kid[2] < bi)) { bk = key64[2]; bi = kid[2]; bs = 2; }
      double rk = bk; int ri = bi;
      #pragma unroll
      for (int off = 32; off > 0; off >>= 1) {
        double ok = __shfl_xor(rk, off, 64);
        int oi = __shfl_xor(ri, off, 64);
        if (ok < rk || (ok == rk && oi < ri)) { rk = ok; ri = oi; }
      }
      if (it > 0 && lane == 0) {
        idx1_i[row * 14 + it - 1] = ri;
        idx1_f[row * 14 + it - 1] = (float)ri;
      }
      if (bi == ri) key64[bs] = 1e300;
    }
  }
}

// ================= K3: FPS (replicates reference's batch-0 gather) =============
__global__ __launch_bounds__(256) void fps_kernel(
    const float* __restrict__ pos, const int* __restrict__ idx_l, int* __restrict__ idx_fps)
{
  int wave = threadIdx.x >> 6, lane = threadIdx.x & 63;
  int r = blockIdx.x * 4 + wave;
  const int* il = idx_l + (size_t)r * 128;
  int gi0 = il[lane], gi1 = il[lane + 64];
  double x0 = (double)pos[gi0*3+0], y0 = (double)pos[gi0*3+1], z0 = (double)pos[gi0*3+2];
  double x1 = (double)pos[gi1*3+0], y1 = (double)pos[gi1*3+1], z1 = (double)pos[gi1*3+2];
  double d0 = 1e10, d1 = 1e10;
  int far = 0;
  int* outp = idx_fps + (size_t)r * 32;
  for (int i = 0; i < 32; ++i) {
    int ownerLane = far & 63;
    int sel = far >> 6;
    int gsel = sel ? gi1 : gi0;
    int gout = __shfl(gsel, ownerLane, 64);
    if (lane == 0) outp[i] = gout;
    double cx = __shfl(sel ? x1 : x0, ownerLane, 64);
    double cy = __shfl(sel ? y1 : y0, ownerLane, 64);
    double cz = __shfl(sel ? z1 : z0, ownerLane, 64);
    double t0 = (x0-cx)*(x0-cx) + (y0-cy)*(y0-cy) + (z0-cz)*(z0-cz);
    double t1 = (x1-cx)*(x1-cx) + (y1-cy)*(y1-cy) + (z1-cz)*(z1-cz);
    d0 = fmin(d0, t0); d1 = fmin(d1, t1);
    double v; int p;
    if (d1 > d0) { v = d1; p = lane + 64; } else { v = d0; p = lane; }
    for (int off = 32; off > 0; off >>= 1) {
      double ov = __shfl_xor(v, off, 64);
      int op = __shfl_xor(p, off, 64);
      if (ov > v || (ov == v && op < p)) { v = ov; p = op; }
    }
    far = p;
  }
}

// ========== K4a: s[gr][o] = x[gr]·W1a[o], v[gr][o] = x[gr]·(W1b-W1a)[o] ==========
__global__ __launch_bounds__(256) void sv_kernel(
    const float* __restrict__ x, const float* __restrict__ W1,
    float* __restrict__ s, float* __restrict__ v)
{
  __shared__ float xs[8][16];
  __shared__ float w1t[512], w1dt[512];
  int tid = threadIdx.x;
  int rbase = blockIdx.x * 8;
  for (int i = tid; i < 512; i += 256) {
    int c = i >> 5, o = i & 31;
    float a = W1[o * 32 + c], bb = W1[o * 32 + 16 + c];
    w1t[i] = a; w1dt[i] = bb - a;
  }
  if (tid < 128) { int rr = tid >> 4, c = tid & 15; xs[rr][c] = x[(size_t)(rbase + rr) * 16 + c]; }
  __syncthreads();
  int rr = tid >> 5, o = tid & 31;
  float sa = 0.f, va = 0.f;
  #pragma unroll
  for (int c = 0; c < 16; ++c) {
    float xv = xs[rr][c];
    sa = fmaf(xv, w1t[c * 32 + o], sa);
    va = fmaf(xv, w1dt[c * 32 + o], va);
  }
  int r = rbase + rr;
  s[(size_t)r * 32 + o] = sa;
  v[(size_t)r * 32 + o] = va;
}

// ========== K4b: h1max + h1 stats via gathered s + v ==========
__global__ __launch_bounds__(256) void h1stats_kernel(
    const float* __restrict__ s, const float* __restrict__ v, const int* __restrict__ idx1_i,
    double* __restrict__ slotsH1, float* __restrict__ h1max)
{
  __shared__ int sidx[8][14];
  __shared__ float sred[256], sred2[256];
  int tid = threadIdx.x;
  int rr = tid >> 5, o = tid & 31;
  int rbase = blockIdx.x * 8;
  if (tid < 112) { int q = tid / 14, k = tid % 14; sidx[q][k] = idx1_i[(rbase + q) * 14 + k]; }
  __syncthreads();
  int r = rbase + rr;
  int broff = r & ~4095;
  float vv = v[(size_t)r * 32 + o];
  float m = -3.4e38f, ls = 0.f, lss = 0.f;
  #pragma unroll
  for (int k = 0; k < 14; ++k) {
    int j = sidx[rr][k];
    float val = s[(size_t)(broff + j) * 32 + o] + vv;
    m = fmaxf(m, val);
    ls += val; lss += val * val;
  }
  h1max[(size_t)r * 32 + o] = m;
  sred[tid] = ls; sred2[tid] = lss;
  __syncthreads();
  if (tid < 32) {
    float s2 = 0.f, ss = 0.f;
    #pragma unroll
    for (int j = 0; j < 8; ++j) { s2 += sred[j * 32 + tid]; ss += sred2[j * 32 + tid]; }
    int slot = blockIdx.x & 255;
    atomicAdd(&slotsH1[slot * 64 + tid], (double)s2);
    atomicAdd(&slotsH1[slot * 64 + 32 + tid], (double)ss);
  }
}

// ---------------- stats finalize: scsh = [sc(C), sh(C)] ----------------
__global__ void finalize_stats_kernel(const double* __restrict__ slots, int C, double cnt,
    const float* __restrict__ g, const float* __restrict__ bta, float* __restrict__ scsh)
{
  int o = threadIdx.x;
  if (o < C) {
    double s = 0.0, ss = 0.0;
    for (int slot = 0; slot < 256; ++slot) { s += slots[slot * 2 * C + o]; ss += slots[slot * 2 * C + C + o]; }
    double mu = s / cnt;
    double var = ss / cnt - mu * mu;
    double rs = 1.0 / sqrt(var + 1e-5);
    float sc = (float)rs * g[o];
    float sh = bta[o] - (float)mu * sc;
    scsh[o] = sc;
    scsh[C + o] = sh;
  }
}

// ========== K5a: f1 = lrelu(affine(h1max)); t = f1·W2a, u = f1·(W2b-W2a) ==========
__global__ __launch_bounds__(256) void tu_kernel(
    const float* __restrict__ h1max, const float* __restrict__ scsh1, const float* __restrict__ W2,
    float* __restrict__ t, float* __restrict__ u)
{
  __shared__ float f1s[4][32];
  __shared__ float w2t[2048], w2dt[2048];
  int tid = threadIdx.x;
  int rbase = blockIdx.x * 4;
  for (int i = tid; i < 2048; i += 256) {
    int c = i >> 6, o = i & 63;
    float a = W2[o * 64 + c], bb = W2[o * 64 + 32 + c];
    w2t[i] = a; w2dt[i] = bb - a;
  }
  if (tid < 128) {
    int rr = tid >> 5, c = tid & 31;
    f1s[rr][c] = lrelu(h1max[(size_t)(rbase + rr) * 32 + c] * scsh1[c] + scsh1[32 + c]);
  }
  __syncthreads();
  int rr = tid >> 6, o = tid & 63;
  float ta = 0.f, ua = 0.f;
  #pragma unroll
  for (int c = 0; c < 32; ++c) {
    float fv = f1s[rr][c];
    ta = fmaf(fv, w2t[c * 64 + o], ta);
    ua = fmaf(fv, w2dt[c * 64 + o], ua);
  }
  int r = rbase + rr;
  t[(size_t)r * 64 + o] = ta;
  u[(size_t)r * 64 + o] = ua;
}

// ========== K5b: h2 stats via gathered t + u ==========
__global__ __launch_bounds__(256) void h2stats_kernel(
    const float* __restrict__ t, const float* __restrict__ u, const int* __restrict__ idx_fps,
    double* __restrict__ slotsH2)
{
  __shared__ int nids[8][32];
  __shared__ float sred[256], sred2[256];
  int tid = threadIdx.x;
  int o = tid & 63, wv = tid >> 6;
  int rbase = blockIdx.x * 8;
  { int q = tid >> 5, k = tid & 31; nids[q][k] = idx_fps[(rbase + q) * 32 + k]; }
  __syncthreads();
  float ls = 0.f, lss = 0.f;
  for (int rr = 0; rr < 8; ++rr) {
    int r = rbase + rr;
    int broff = r & ~4095;
    float uo = u[(size_t)r * 64 + o];
    #pragma unroll
    for (int i = 0; i < 8; ++i) {
      int k = wv + 4 * i;
      float val = t[(size_t)(broff + nids[rr][k]) * 64 + o] + uo;
      ls += val; lss += val * val;
    }
  }
  sred[tid] = ls; sred2[tid] = lss;
  __syncthreads();
  if (tid < 64) {
    float s2 = sred[tid] + sred[tid + 64] + sred[tid + 128] + sred[tid + 192];
    float ss = sred2[tid] + sred2[tid + 64] + sred2[tid + 128] + sred2[tid + 192];
    int slot = blockIdx.x & 255;
    atomicAdd(&slotsH2[slot * 128 + tid], (double)s2);
    atomicAdd(&slotsH2[slot * 128 + 64 + tid], (double)ss);
  }
}

// ========== K6: h3 = lrelu(affine(t[nid]+u))·W3ᵀ, stats + channel max ==========
#define ROWS3 8
__global__ __launch_bounds__(256, 4) void h3_kernel(
    const float* __restrict__ t, const float* __restrict__ u, const int* __restrict__ idx_fps,
    const float* __restrict__ W3, const float* __restrict__ scsh2,
    double* __restrict__ slotsH3, float* __restrict__ h3max)
{
  __shared__ float h2lds[2048];
  __shared__ float wmax[256];
  __shared__ float sred[256], sred2[256];
  __shared__ int nids[ROWS3][32];
  int tid = threadIdx.x;
  int o = tid & 63, wv = tid >> 6;
  float4 w3r[16];
  const float4* w3p = (const float4*)(W3 + o * 64);
  #pragma unroll
  for (int j = 0; j < 16; ++j) w3r[j] = w3p[j];
  float sc2o = scsh2[o], sh2o = scsh2[64 + o];
  int rbase = blockIdx.x * ROWS3;
  { int q = tid >> 5, k = tid & 31; nids[q][k] = idx_fps[(rbase + q) * 32 + k]; }
  float ls = 0.f, lss = 0.f;
  __syncthreads();
  for (int rr = 0; rr < ROWS3; ++rr) {
    int r = rbase + rr;
    int broff = r & ~4095;
    float uo = u[(size_t)r * 64 + o];
    #pragma unroll
    for (int i = 0; i < 8; ++i) {
      int k = wv + 4 * i;
      float val = t[(size_t)(broff + nids[rr][k]) * 64 + o] + uo;
      h2lds[k * 64 + o] = lrelu(val * sc2o + sh2o);
    }
    __syncthreads();
    float kmax = -3.4e38f;
    #pragma unroll
    for (int i = 0; i < 8; ++i) {
      int k = wv + 4 * i;
      const float4* hp = (const float4*)(h2lds + k * 64);
      float acc = 0.f;
      #pragma unroll
      for (int j = 0; j < 16; ++j) {
        float4 h = hp[j];
        acc = fmaf(h.x, w3r[j].x, acc); acc = fmaf(h.y, w3r[j].y, acc);
        acc = fmaf(h.z, w3r[j].z, acc); acc = fmaf(h.w, w3r[j].w, acc);
      }
      ls += acc; lss += acc * acc;
      kmax = fmaxf(kmax, acc);
    }
    wmax[tid] = kmax;
    __syncthreads();
    if (tid < 64) {
      float m = fmaxf(fmaxf(wmax[tid], wmax[64 + tid]), fmaxf(wmax[128 + tid], wmax[192 + tid]));
      h3max[(size_t)r * 64 + tid] = m;
    }
  }
  sred[tid] = ls; sred2[tid] = lss;
  __syncthreads();
  if (tid < 64) {
    float s2 = sred[tid] + sred[tid + 64] + sred[tid + 128] + sred[tid + 192];
    float ss = sred2[tid] + sred2[tid + 64] + sred2[tid + 128] + sred2[tid + 192];
    int slot = blockIdx.x & 255;
    atomicAdd(&slotsH3[slot * 128 + tid], (double)s2);
    atomicAdd(&slotsH3[slot * 128 + 64 + tid], (double)ss);
  }
}

// ---------------- K10: out = lrelu(affine(h3max)) ----------------
__global__ void out_kernel(const float* __restrict__ h3max, const float* __restrict__ scsh3,
                           float* __restrict__ out)
{
  int i = blockIdx.x * 256 + threadIdx.x;
  int o = i & 63;
  out[i] = lrelu(h3max[i] * scsh3[o] + scsh3[64 + o]);
}

extern "C" void kernel_launch(void* const* d_in, const int* in_sizes, int n_in,
                              void* d_out, int out_size, void* d_ws, size_t ws_size,
                              hipStream_t stream) {
  (void)in_sizes; (void)n_in; (void)out_size; (void)ws_size;
  const float* x   = (const float*)d_in[0];
  const float* pos = (const float*)d_in[1];
  const float* W1  = (const float*)d_in[2];
  const float* g1  = (const float*)d_in[3];
  const float* b1  = (const float*)d_in[4];
  const float* W2  = (const float*)d_in[5];
  const float* g2  = (const float*)d_in[6];
  const float* b2  = (const float*)d_in[7];
  const float* W3  = (const float*)d_in[8];
  const float* g3  = (const float*)d_in[9];
  const float* b3  = (const float*)d_in[10];

  float* out      = (float*)d_out;             // (4,4096,64) f32
  float* out_idx1 = out + 1048576;             // (4,4096,14) written as float(idx)
  // scratch inside the d_out "out" region (overwritten by out_kernel at the end):
  float* xT       = out;                       // 4 x 16 x 4096 f32 = 1 MB

  char* ws = (char*)d_ws;
  double* slotsH1 = (double*)(ws + 0);         // 256 x 64 double
  double* slotsH2 = (double*)(ws + 131072);    // 256 x 128 double
  double* slotsH3 = (double*)(ws + 393216);    // 256 x 128 double
  float*  scsh1   = (float*)(ws + 655360);     // 64 f
  float*  scsh2   = (float*)(ws + 655616);     // 128 f
  float*  scsh3   = (float*)(ws + 656128);     // 128 f
  float*  sqx     = (float*)(ws + 786432);     // 16384 f
  float*  posT    = (float*)(ws + 851968);     // 4 x 3 x 4096 f = 192 KB (ends at 1048576)
  int*    idx_l   = (int*)(ws + 1048576);      // 16384 x 128 (freed after fps)
  float*  t_buf   = (float*)(ws + 1048576);    // 16384 x 64 f32 (overlaps idx_l)
  float*  u_buf   = (float*)(ws + 5242880);    // 16384 x 64 f32 (overlaps idx_l)
  int*    idx_fps = (int*)(ws + 9437184);      // 16384 x 32
  int*    idx1_i  = (int*)(ws + 11534336);     // 16384 x 14
  float*  h1max   = (float*)(ws + 12451840);   // 16384 x 32
  float*  s_buf   = (float*)(ws + 14548992);   // 16384 x 32
  float*  v_buf   = (float*)(ws + 16646144);   // 16384 x 32
  float*  h3max   = (float*)(ws + 18743296);   // 16384 x 64

  hipMemsetAsync(d_ws, 0, 656640, stream);     // zero stat accumulators

  xpose_kernel   <<<dim3(256),  dim3(256), 0, stream>>>(x, xT, sqx);
  ppose_kernel   <<<dim3(64),   dim3(192), 0, stream>>>(pos, posT);
  knn_pos_kernel <<<dim3(2048), dim3(512), 0, stream>>>(pos, posT, idx_l, idx1_i, out_idx1);
  knn_feat_kernel<<<dim3(4096), dim3(256), 0, stream>>>(x, xT, sqx, idx1_i, out_idx1);
  fps_kernel     <<<dim3(4096), dim3(256), 0, stream>>>(pos, idx_l, idx_fps);
  // idx_l dead from here; t/u reuse its space
  sv_kernel      <<<dim3(2048), dim3(256), 0, stream>>>(x, W1, s_buf, v_buf);
  h1stats_kernel <<<dim3(2048), dim3(256), 0, stream>>>(s_buf, v_buf, idx1_i, slotsH1, h1max);
  finalize_stats_kernel<<<dim3(1), dim3(64), 0, stream>>>(slotsH1, 32, 229376.0, g1, b1, scsh1);
  tu_kernel      <<<dim3(4096), dim3(256), 0, stream>>>(h1max, scsh1, W2, t_buf, u_buf);
  h2stats_kernel <<<dim3(2048), dim3(256), 0, stream>>>(t_buf, u_buf, idx_fps, slotsH2);
  finalize_stats_kernel<<<dim3(1), dim3(64), 0, stream>>>(slotsH2, 64, 524288.0, g2, b2, scsh2);
  h3_kernel      <<<dim3(2048), dim3(256), 0, stream>>>(t_buf, u_buf, idx_fps, W3, scsh2, slotsH3, h3max);
  finalize_stats_kernel<<<dim3(1), dim3(64), 0, stream>>>(slotsH3, 64, 524288.0, g3, b3, scsh3);
  out_kernel     <<<dim3(4096), dim3(256), 0, stream>>>(h3max, scsh3, out);
}

// Round 10
// 722.593 us; speedup vs baseline: 1.0142x; 1.0142x over previous
//
#include <hip/hip_runtime.h>

#define NPTS 4096
#define BNROWS 16384
#define XSTR 4160            // padded column stride for xT (floats)
#define PSTR 4160            // padded column stride for posT (floats)

__device__ __forceinline__ float lrelu(float h) { return h > 0.f ? h : 0.2f * h; }

// wave-local LDS fence: orders this wave's LDS ops (lockstep wave64 + lgkmcnt)
#define WSYNC asm volatile("s_waitcnt lgkmcnt(0)" ::: "memory")

__device__ __forceinline__ float rfl(float v) {
  return __int_as_float(__builtin_amdgcn_readfirstlane(__float_as_int(v)));
}

// ========== K0a: transpose x -> xT[b][c][j] (padded stride) + norms ==========
__global__ __launch_bounds__(256) void xpose_kernel(
    const float* __restrict__ x, float* __restrict__ xT, float* __restrict__ sqx)
{
  __shared__ float tile[64][17];
  int t = threadIdx.x;
  int j0 = blockIdx.x * 64;         // global row base
  int b = j0 >> 12;
  int jloc0 = j0 & 4095;
  int p = t >> 2, q = t & 3;
  const float4* xp = (const float4*)(x + (size_t)(j0 + p) * 16);
  float4 v = xp[q];
  tile[p][q*4+0] = v.x; tile[p][q*4+1] = v.y; tile[p][q*4+2] = v.z; tile[p][q*4+3] = v.w;
  __syncthreads();
  int jj = t & 63, chi = t >> 6;
  float* xTb = xT + (size_t)b * (16 * XSTR);
  #pragma unroll
  for (int i = 0; i < 4; ++i) {
    int c = chi * 4 + i;
    xTb[c * XSTR + jloc0 + jj] = tile[jj][c];
  }
  if (t < 64) {
    float s = 0.f;
    #pragma unroll
    for (int c = 0; c < 16; ++c) { float vv = tile[t][c]; s = fmaf(vv, vv, s); }
    sqx[j0 + t] = s;
  }
}

// ========== K0b: transpose pos -> posT[b][c][j] (padded stride) ==========
__global__ __launch_bounds__(192) void ppose_kernel(
    const float* __restrict__ pos, float* __restrict__ posT)
{
  __shared__ float raw[768];
  int t = threadIdx.x;
  int j0 = blockIdx.x * 256;
  int b = j0 >> 12;
  int jloc0 = j0 & 4095;
  const float4* pp = (const float4*)(pos + (size_t)j0 * 3);
  float4 v = pp[t];
  raw[t*4+0] = v.x; raw[t*4+1] = v.y; raw[t*4+2] = v.z; raw[t*4+3] = v.w;
  __syncthreads();
  float* pTb = posT + (size_t)b * (3 * PSTR);
  #pragma unroll
  for (int i = 0; i < 4; ++i) {
    int idx = t + 192 * i;          // 0..767
    int c = idx >> 8, jj = idx & 255;
    pTb[c * PSTR + jloc0 + jj] = raw[jj * 3 + c];
  }
}

// ================= K1: pos 128-NN (sorted) + idx_pos ==================
__global__ __launch_bounds__(512) void knn_pos_kernel(
    const float* __restrict__ pos, const float* __restrict__ posT,
    int* __restrict__ idx_l, int* __restrict__ idx1_i, float* __restrict__ idx1_f)
{
  __shared__ unsigned long long cKey[8][512];
  __shared__ unsigned int cCnt[8];
  int tid = threadIdx.x;
  int w = tid >> 6, lane = tid & 63;
  int r = blockIdx.x * 8 + w;
  int b = r >> 12, n = r & 4095;
  const float* pb = pos + (size_t)b * NPTS * 3;
  const float* pT = posT + (size_t)b * (3 * PSTR);
  float cx = pb[n*3+0], cy = pb[n*3+1], cz = pb[n*3+2];
  if (lane == 0) cCnt[w] = 0u;
  WSYNC;

  unsigned int qp[32];
  int m1 = 65536, m2 = 65536, m3 = 65536;
  #pragma unroll
  for (int t = 0; t < 32; ++t) {
    unsigned int wq = 0u;
    #pragma unroll
    for (int h = 0; h < 2; ++h) {
      int j = (2*t + h) * 64 + lane;
      float dx = cx - pT[j], dy = cy - pT[PSTR + j], dz = cz - pT[2*PSTR + j];
      float d2 = dx*dx + dy*dy + dz*dz;
      int q = (int)(d2 * 1000.0f);
      q = q < 0 ? 0 : (q > 65535 ? 65535 : q);
      wq |= ((unsigned int)q) << (16*h);
      int nm1 = min(m1, q);
      int nm2 = min(m2, max(m1, q));
      int nm3 = min(m3, max(m2, q));
      m1 = nm1; m2 = nm2; m3 = nm3;
    }
    qp[t] = wq;
  }
  // smallest qt with >=43 lanes having 3rd-min <= qt  => >=129 pts <= qt
  int lo = 0, hi = 65535;
  #pragma unroll
  for (int it = 0; it < 16; ++it) {
    int mid = (lo + hi) >> 1;
    int cnt = __popcll(__ballot(m3 <= mid));
    if (cnt >= 43) hi = mid; else lo = mid + 1;
  }
  unsigned int qt = (unsigned int)lo + 2u;   // +2 bucket slack (fp32 vs fp64)

  #pragma unroll
  for (int t = 0; t < 32; ++t) {
    unsigned int wq = qp[t];
    unsigned int q0 = wq & 0xffffu, q1 = wq >> 16;
    if (q0 <= qt) { unsigned int p = atomicAdd(&cCnt[w], 1u); if (p < 512u) cKey[w][p] = (unsigned long long)((2*t)*64 + lane); }
    if (q1 <= qt) { unsigned int p = atomicAdd(&cCnt[w], 1u); if (p < 512u) cKey[w][p] = (unsigned long long)((2*t+1)*64 + lane); }
  }
  WSYNC;
  unsigned int nc = cCnt[w]; if (nc > 512u) nc = 512u;
  int M = (nc <= 256u) ? 256 : 512;
  int EPL = M >> 6;

  // exact fp64 rerank in place -> packed (key|idx), pad with ~0
  double cxd = (double)cx, cyd = (double)cy, czd = (double)cz;
  for (int t = 0; t < EPL; ++t) {
    int c = lane + (t << 6);
    unsigned long long kk = ~0ull;
    if (c < (int)nc) {
      int id = (int)cKey[w][c];
      double dx = cxd - (double)pb[id*3+0];
      double dy = cyd - (double)pb[id*3+1];
      double dz = czd - (double)pb[id*3+2];
      double d2 = dx*dx + dy*dy + dz*dz;
      unsigned long long bits = (unsigned long long)__double_as_longlong(d2);
      kk = (bits & ~0xFFFull) | (unsigned long long)(unsigned int)id;
    }
    cKey[w][c] = kk;
  }
  WSYNC;

  // wave-private bitonic-M on packed keys, ascending
  for (int k = 2; k <= M; k <<= 1) {
    for (int j = k >> 1; j > 0; j >>= 1) {
      for (int t = 0; t < EPL; ++t) {
        int i = lane + (t << 6);
        int ixj = i ^ j;
        if (ixj > i) {
          unsigned long long ka = cKey[w][i], kb = cKey[w][ixj];
          bool up = ((i & k) == 0);
          if ((ka > kb) == up) { cKey[w][i] = kb; cKey[w][ixj] = ka; }
        }
      }
      WSYNC;
    }
  }
  idx_l[(size_t)r * 128 + lane]      = (int)(cKey[w][lane] & 0xFFFull);
  idx_l[(size_t)r * 128 + lane + 64] = (int)(cKey[w][lane + 64] & 0xFFFull);
  if (lane < 6) {
    int v = (int)(cKey[w][1 + lane] & 0xFFFull);
    idx1_i[r * 14 + 8 + lane] = v;
    idx1_f[r * 14 + 8 + lane] = (float)v;
  }
}

// ================= K2: feature 8-NN (excl self), v4 + padded xT ==================
__global__ __launch_bounds__(256) void knn_feat_kernel(
    const float* __restrict__ x, const float* __restrict__ xT,
    const float* __restrict__ sqx,
    int* __restrict__ idx1_i, float* __restrict__ idx1_f)
{
  __shared__ float lmin[4][256];
  __shared__ int cand[4][192];
  __shared__ unsigned int cCnt[4];
  __shared__ float qtS[4];
  __shared__ float ctrf[4][16];
  int tid = threadIdx.x;
  int w = tid >> 6, lane = tid & 63;
  int rbase = blockIdx.x * 4;
  int b = rbase >> 12;
  const float* xb  = x  + (size_t)b * NPTS * 16;
  const float* xTb = xT + (size_t)b * (16 * XSTR);
  const float* sqb = sqx + b * NPTS;

  if (tid < 64) {
    int rr = tid >> 4, c = tid & 15;
    ctrf[rr][c] = xb[(size_t)((rbase + rr) & 4095) * 16 + c];   // batch-local row
  }
  if (tid < 4) cCnt[tid] = 0u;
  __syncthreads();

  // centers: cm = -2*ctr, c2 = |ctr|^2 (wave-uniform)
  float cm[4][16], c2[4];
  #pragma unroll
  for (int rr = 0; rr < 4; ++rr) {
    float s = 0.f;
    #pragma unroll
    for (int c = 0; c < 16; ++c) {
      float v = ctrf[rr][c];
      cm[rr][c] = rfl(-2.0f * v);
      s = fmaf(v, v, s);
    }
    c2[rr] = rfl(s);
  }

  // distance pass: coalesced padded xT dword loads, fp32 Gram keys in registers
  float key[4][16];
  float fk[4] = {3.4e38f, 3.4e38f, 3.4e38f, 3.4e38f};
  #pragma unroll
  for (int pt = 0; pt < 16; ++pt) {
    int j = tid + 256 * pt;
    float sqj = sqb[j];
    float a0 = sqj + c2[0], a1 = sqj + c2[1], a2 = sqj + c2[2], a3 = sqj + c2[3];
    #pragma unroll
    for (int c = 0; c < 16; ++c) {
      float va = xTb[c * XSTR + j];
      a0 = fmaf(va, cm[0][c], a0);
      a1 = fmaf(va, cm[1][c], a1);
      a2 = fmaf(va, cm[2][c], a2);
      a3 = fmaf(va, cm[3][c], a3);
    }
    key[0][pt] = a0; key[1][pt] = a1; key[2][pt] = a2; key[3][pt] = a3;
    fk[0] = fminf(fk[0], a0); fk[1] = fminf(fk[1], a1);
    fk[2] = fminf(fk[2], a2); fk[3] = fminf(fk[3], a3);
  }
  #pragma unroll
  for (int rr = 0; rr < 4; ++rr) lmin[rr][tid] = fk[rr];
  __syncthreads();

  // wave w: threshold for row w = 10th smallest of 256 thread-minima
  {
    float lv0 = lmin[w][lane], lv1 = lmin[w][lane + 64];
    float lv2 = lmin[w][lane + 128], lv3 = lmin[w][lane + 192];
    unsigned int lo = 0u, hi = 0x7F800000u;
    for (int it = 0; it < 31; ++it) {
      unsigned int mid = (lo + hi) >> 1;
      float midf = __uint_as_float(mid);
      int cnt = __popcll(__ballot(lv0 <= midf)) + __popcll(__ballot(lv1 <= midf))
              + __popcll(__ballot(lv2 <= midf)) + __popcll(__ballot(lv3 <= midf));
      if (cnt >= 10) hi = mid; else lo = mid + 1;
    }
    if (lane == 0) qtS[w] = __uint_as_float(hi) * 1.0002f + 1e-3f;
  }
  __syncthreads();

  // compaction
  {
    float q0 = qtS[0], q1 = qtS[1], q2 = qtS[2], q3 = qtS[3];
    #pragma unroll
    for (int pt = 0; pt < 16; ++pt) {
      int j = tid + 256 * pt;
      if (key[0][pt] <= q0) { unsigned int p = atomicAdd(&cCnt[0], 1u); if (p < 192u) cand[0][p] = j; }
      if (key[1][pt] <= q1) { unsigned int p = atomicAdd(&cCnt[1], 1u); if (p < 192u) cand[1][p] = j; }
      if (key[2][pt] <= q2) { unsigned int p = atomicAdd(&cCnt[2], 1u); if (p < 192u) cand[2][p] = j; }
      if (key[3][pt] <= q3) { unsigned int p = atomicAdd(&cCnt[3], 1u); if (p < 192u) cand[3][p] = j; }
    }
  }
  __syncthreads();

  // wave w: fp64 rerank + 9 sorted min-extractions (rank0 = self, dropped)
  {
    int nc = (int)cCnt[w]; if (nc > 192) nc = 192;
    double key64[3]; int kid[3];
    #pragma unroll
    for (int s = 0; s < 3; ++s) {
      int c = lane + 64*s;
      if (c < nc) {
        int id = cand[w][c];
        const float4* xp = (const float4*)(xb + (size_t)id * 16);
        float4 q0 = xp[0], q1 = xp[1], q2 = xp[2], q3 = xp[3];
        float xv[16] = {q0.x,q0.y,q0.z,q0.w, q1.x,q1.y,q1.z,q1.w,
                        q2.x,q2.y,q2.z,q2.w, q3.x,q3.y,q3.z,q3.w};
        double acc = 0.0;
        #pragma unroll
        for (int c2i = 0; c2i < 16; ++c2i) { double d = (double)ctrf[w][c2i] - (double)xv[c2i]; acc += d * d; }
        key64[s] = acc; kid[s] = id;
      } else { key64[s] = 1e300; kid[s] = 0x7fffffff; }
    }
    int row = rbase + w;
    for (int it = 0; it < 9; ++it) {
      double bk = key64[0]; int bi = kid[0], bs = 0;
      if (key64[1] < bk || (key64[1] == bk && kid[1] < bi)) { bk = key64[1]; bi = kid[1]; bs = 1; }
      if (key64[2] < bk || (key64[2] == bk && kid[2] < bi)) { bk = key64[2]; bi = kid[2]; bs = 2; }
      double rk = bk; int ri = bi;
      #pragma unroll
      for (int off = 32; off > 0; off >>= 1) {
        double ok = __shfl_xor(rk, off, 64);
        int oi = __shfl_xor(ri, off, 64);
        if (ok < rk || (ok == rk && oi < ri)) { rk = ok; ri = oi; }
      }
      if (it > 0 && lane == 0) {
        idx1_i[row * 14 + it - 1] = ri;
        idx1_f[row * 14 + it - 1] = (float)ri;
      }
      if (bi == ri) key64[bs] = 1e300;
    }
  }
}

// ================= K3: FPS (replicates reference's batch-0 gather) =============
__global__ __launch_bounds__(256) void fps_kernel(
    const float* __restrict__ pos, const int* __restrict__ idx_l, int* __restrict__ idx_fps)
{
  int wave = threadIdx.x >> 6, lane = threadIdx.x & 63;
  int r = blockIdx.x * 4 + wave;
  const int* il = idx_l + (size_t)r * 128;
  int gi0 = il[lane], gi1 = il[lane + 64];
  double x0 = (double)pos[gi0*3+0], y0 = (double)pos[gi0*3+1], z0 = (double)pos[gi0*3+2];
  double x1 = (double)pos[gi1*3+0], y1 = (double)pos[gi1*3+1], z1 = (double)pos[gi1*3+2];
  double d0 = 1e10, d1 = 1e10;
  int far = 0;
  int* outp = idx_fps + (size_t)r * 32;
  for (int i = 0; i < 32; ++i) {
    int ownerLane = far & 63;
    int sel = far >> 6;
    int gsel = sel ? gi1 : gi0;
    int gout = __shfl(gsel, ownerLane, 64);
    if (lane == 0) outp[i] = gout;
    double cx = __shfl(sel ? x1 : x0, ownerLane, 64);
    double cy = __shfl(sel ? y1 : y0, ownerLane, 64);
    double cz = __shfl(sel ? z1 : z0, ownerLane, 64);
    double t0 = (x0-cx)*(x0-cx) + (y0-cy)*(y0-cy) + (z0-cz)*(z0-cz);
    double t1 = (x1-cx)*(x1-cx) + (y1-cy)*(y1-cy) + (z1-cz)*(z1-cz);
    d0 = fmin(d0, t0); d1 = fmin(d1, t1);
    double v; int p;
    if (d1 > d0) { v = d1; p = lane + 64; } else { v = d0; p = lane; }
    for (int off = 32; off > 0; off >>= 1) {
      double ov = __shfl_xor(v, off, 64);
      int op = __shfl_xor(p, off, 64);
      if (ov > v || (ov == v && op < p)) { v = ov; p = op; }
    }
    far = p;
  }
}

// ========== K4a: s[gr][o] = x[gr]·W1a[o], v[gr][o] = x[gr]·(W1b-W1a)[o] ==========
__global__ __launch_bounds__(256) void sv_kernel(
    const float* __restrict__ x, const float* __restrict__ W1,
    float* __restrict__ s, float* __restrict__ v)
{
  __shared__ float xs[8][16];
  __shared__ float w1t[512], w1dt[512];
  int tid = threadIdx.x;
  int rbase = blockIdx.x * 8;
  for (int i = tid; i < 512; i += 256) {
    int c = i >> 5, o = i & 31;
    float a = W1[o * 32 + c], bb = W1[o * 32 + 16 + c];
    w1t[i] = a; w1dt[i] = bb - a;
  }
  if (tid < 128) { int rr = tid >> 4, c = tid & 15; xs[rr][c] = x[(size_t)(rbase + rr) * 16 + c]; }
  __syncthreads();
  int rr = tid >> 5, o = tid & 31;
  float sa = 0.f, va = 0.f;
  #pragma unroll
  for (int c = 0; c < 16; ++c) {
    float xv = xs[rr][c];
    sa = fmaf(xv, w1t[c * 32 + o], sa);
    va = fmaf(xv, w1dt[c * 32 + o], va);
  }
  int r = rbase + rr;
  s[(size_t)r * 32 + o] = sa;
  v[(size_t)r * 32 + o] = va;
}

// ========== K4b: h1max + h1 stats via gathered s + v ==========
__global__ __launch_bounds__(256) void h1stats_kernel(
    const float* __restrict__ s, const float* __restrict__ v, const int* __restrict__ idx1_i,
    double* __restrict__ slotsH1, float* __restrict__ h1max)
{
  __shared__ int sidx[8][14];
  __shared__ float sred[256], sred2[256];
  int tid = threadIdx.x;
  int rr = tid >> 5, o = tid & 31;
  int rbase = blockIdx.x * 8;
  if (tid < 112) { int q = tid / 14, k = tid % 14; sidx[q][k] = idx1_i[(rbase + q) * 14 + k]; }
  __syncthreads();
  int r = rbase + rr;
  int broff = r & ~4095;
  float vv = v[(size_t)r * 32 + o];
  float m = -3.4e38f, ls = 0.f, lss = 0.f;
  #pragma unroll
  for (int k = 0; k < 14; ++k) {
    int j = sidx[rr][k];
    float val = s[(size_t)(broff + j) * 32 + o] + vv;
    m = fmaxf(m, val);
    ls += val; lss += val * val;
  }
  h1max[(size_t)r * 32 + o] = m;
  sred[tid] = ls; sred2[tid] = lss;
  __syncthreads();
  if (tid < 32) {
    float s2 = 0.f, ss = 0.f;
    #pragma unroll
    for (int j = 0; j < 8; ++j) { s2 += sred[j * 32 + tid]; ss += sred2[j * 32 + tid]; }
    int slot = blockIdx.x & 255;
    atomicAdd(&slotsH1[slot * 64 + tid], (double)s2);
    atomicAdd(&slotsH1[slot * 64 + 32 + tid], (double)ss);
  }
}

// ---------------- stats finalize: scsh = [sc(C), sh(C)] ----------------
__global__ void finalize_stats_kernel(const double* __restrict__ slots, int C, double cnt,
    const float* __restrict__ g, const float* __restrict__ bta, float* __restrict__ scsh)
{
  int o = threadIdx.x;
  if (o < C) {
    double s = 0.0, ss = 0.0;
    for (int slot = 0; slot < 256; ++slot) { s += slots[slot * 2 * C + o]; ss += slots[slot * 2 * C + C + o]; }
    double mu = s / cnt;
    double var = ss / cnt - mu * mu;
    double rs = 1.0 / sqrt(var + 1e-5);
    float sc = (float)rs * g[o];
    float sh = bta[o] - (float)mu * sc;
    scsh[o] = sc;
    scsh[C + o] = sh;
  }
}

// ========== K5a: f1 = lrelu(affine(h1max)); t = f1·W2a, u = f1·(W2b-W2a) ==========
__global__ __launch_bounds__(256) void tu_kernel(
    const float* __restrict__ h1max, const float* __restrict__ scsh1, const float* __restrict__ W2,
    float* __restrict__ t, float* __restrict__ u)
{
  __shared__ float f1s[4][32];
  __shared__ float w2t[2048], w2dt[2048];
  int tid = threadIdx.x;
  int rbase = blockIdx.x * 4;
  for (int i = tid; i < 2048; i += 256) {
    int c = i >> 6, o = i & 63;
    float a = W2[o * 64 + c], bb = W2[o * 64 + 32 + c];
    w2t[i] = a; w2dt[i] = bb - a;
  }
  if (tid < 128) {
    int rr = tid >> 5, c = tid & 31;
    f1s[rr][c] = lrelu(h1max[(size_t)(rbase + rr) * 32 + c] * scsh1[c] + scsh1[32 + c]);
  }
  __syncthreads();
  int rr = tid >> 6, o = tid & 63;
  float ta = 0.f, ua = 0.f;
  #pragma unroll
  for (int c = 0; c < 32; ++c) {
    float fv = f1s[rr][c];
    ta = fmaf(fv, w2t[c * 64 + o], ta);
    ua = fmaf(fv, w2dt[c * 64 + o], ua);
  }
  int r = rbase + rr;
  t[(size_t)r * 64 + o] = ta;
  u[(size_t)r * 64 + o] = ua;
}

// ========== K5b: h2 stats via gathered t + u ==========
__global__ __launch_bounds__(256) void h2stats_kernel(
    const float* __restrict__ t, const float* __restrict__ u, const int* __restrict__ idx_fps,
    double* __restrict__ slotsH2)
{
  __shared__ int nids[8][32];
  __shared__ float sred[256], sred2[256];
  int tid = threadIdx.x;
  int o = tid & 63, wv = tid >> 6;
  int rbase = blockIdx.x * 8;
  { int q = tid >> 5, k = tid & 31; nids[q][k] = idx_fps[(rbase + q) * 32 + k]; }
  __syncthreads();
  float ls = 0.f, lss = 0.f;
  for (int rr = 0; rr < 8; ++rr) {
    int r = rbase + rr;
    int broff = r & ~4095;
    float uo = u[(size_t)r * 64 + o];
    #pragma unroll
    for (int i = 0; i < 8; ++i) {
      int k = wv + 4 * i;
      float val = t[(size_t)(broff + nids[rr][k]) * 64 + o] + uo;
      ls += val; lss += val * val;
    }
  }
  sred[tid] = ls; sred2[tid] = lss;
  __syncthreads();
  if (tid < 64) {
    float s2 = sred[tid] + sred[tid + 64] + sred[tid + 128] + sred[tid + 192];
    float ss = sred2[tid] + sred2[tid + 64] + sred2[tid + 128] + sred2[tid + 192];
    int slot = blockIdx.x & 255;
    atomicAdd(&slotsH2[slot * 128 + tid], (double)s2);
    atomicAdd(&slotsH2[slot * 128 + 64 + tid], (double)ss);
  }
}

// ========== K6: h3 = lrelu(affine(t[nid]+u))·W3ᵀ, stats + channel max ==========
#define ROWS3 8
__global__ __launch_bounds__(256, 4) void h3_kernel(
    const float* __restrict__ t, const float* __restrict__ u, const int* __restrict__ idx_fps,
    const float* __restrict__ W3, const float* __restrict__ scsh2,
    double* __restrict__ slotsH3, float* __restrict__ h3max)
{
  __shared__ float h2lds[2048];
  __shared__ float wmax[256];
  __shared__ float sred[256], sred2[256];
  __shared__ int nids[ROWS3][32];
  int tid = threadIdx.x;
  int o = tid & 63, wv = tid >> 6;
  float4 w3r[16];
  const float4* w3p = (const float4*)(W3 + o * 64);
  #pragma unroll
  for (int j = 0; j < 16; ++j) w3r[j] = w3p[j];
  float sc2o = scsh2[o], sh2o = scsh2[64 + o];
  int rbase = blockIdx.x * ROWS3;
  { int q = tid >> 5, k = tid & 31; nids[q][k] = idx_fps[(rbase + q) * 32 + k]; }
  float ls = 0.f, lss = 0.f;
  __syncthreads();
  for (int rr = 0; rr < ROWS3; ++rr) {
    int r = rbase + rr;
    int broff = r & ~4095;
    float uo = u[(size_t)r * 64 + o];
    #pragma unroll
    for (int i = 0; i < 8; ++i) {
      int k = wv + 4 * i;
      float val = t[(size_t)(broff + nids[rr][k]) * 64 + o] + uo;
      h2lds[k * 64 + o] = lrelu(val * sc2o + sh2o);
    }
    __syncthreads();
    float kmax = -3.4e38f;
    #pragma unroll
    for (int i = 0; i < 8; ++i) {
      int k = wv + 4 * i;
      const float4* hp = (const float4*)(h2lds + k * 64);
      float acc = 0.f;
      #pragma unroll
      for (int j = 0; j < 16; ++j) {
        float4 h = hp[j];
        acc = fmaf(h.x, w3r[j].x, acc); acc = fmaf(h.y, w3r[j].y, acc);
        acc = fmaf(h.z, w3r[j].z, acc); acc = fmaf(h.w, w3r[j].w, acc);
      }
      ls += acc; lss += acc * acc;
      kmax = fmaxf(kmax, acc);
    }
    wmax[tid] = kmax;
    __syncthreads();
    if (tid < 64) {
      float m = fmaxf(fmaxf(wmax[tid], wmax[64 + tid]), fmaxf(wmax[128 + tid], wmax[192 + tid]));
      h3max[(size_t)r * 64 + tid] = m;
    }
  }
  sred[tid] = ls; sred2[tid] = lss;
  __syncthreads();
  if (tid < 64) {
    float s2 = sred[tid] + sred[tid + 64] + sred[tid + 128] + sred[tid + 192];
    float ss = sred2[tid] + sred2[tid + 64] + sred2[tid + 128] + sred2[tid + 192];
    int slot = blockIdx.x & 255;
    atomicAdd(&slotsH3[slot * 128 + tid], (double)s2);
    atomicAdd(&slotsH3[slot * 128 + 64 + tid], (double)ss);
  }
}

// ---------------- K10: out = lrelu(affine(h3max)) ----------------
__global__ void out_kernel(const float* __restrict__ h3max, const float* __restrict__ scsh3,
                           float* __restrict__ out)
{
  int i = blockIdx.x * 256 + threadIdx.x;
  int o = i & 63;
  out[i] = lrelu(h3max[i] * scsh3[o] + scsh3[64 + o]);
}

extern "C" void kernel_launch(void* const* d_in, const int* in_sizes, int n_in,
                              void* d_out, int out_size, void* d_ws, size_t ws_size,
                              hipStream_t stream) {
  (void)in_sizes; (void)n_in; (void)out_size; (void)ws_size;
  const float* x   = (const float*)d_in[0];
  const float* pos = (const float*)d_in[1];
  const float* W1  = (const float*)d_in[2];
  const float* g1  = (const float*)d_in[3];
  const float* b1  = (const float*)d_in[4];
  const float* W2  = (const float*)d_in[5];
  const float* g2  = (const float*)d_in[6];
  const float* b2  = (const float*)d_in[7];
  const float* W3  = (const float*)d_in[8];
  const float* g3  = (const float*)d_in[9];
  const float* b3  = (const float*)d_in[10];

  float* out      = (float*)d_out;             // (4,4096,64) f32
  float* out_idx1 = out + 1048576;             // (4,4096,14) written as float(idx)
  // scratch inside the d_out "out" region (overwritten by out_kernel at the end):
  float* xT       = out;                       // 4 x 16 x 4160 f32 = 1.06 MB... fits (out = 4 MB)
  float* posT     = out + 300000;              // 4 x 3 x 4160 f32 = 200 KB

  char* ws = (char*)d_ws;
  double* slotsH1 = (double*)(ws + 0);         // 256 x 64 double
  double* slotsH2 = (double*)(ws + 131072);    // 256 x 128 double
  double* slotsH3 = (double*)(ws + 393216);    // 256 x 128 double
  float*  scsh1   = (float*)(ws + 655360);     // 64 f
  float*  scsh2   = (float*)(ws + 655616);     // 128 f
  float*  scsh3   = (float*)(ws + 656128);     // 128 f
  float*  sqx     = (float*)(ws + 786432);     // 16384 f
  int*    idx_l   = (int*)(ws + 1048576);      // 16384 x 128 (freed after fps)
  float*  t_buf   = (float*)(ws + 1048576);    // 16384 x 64 f32 (overlaps idx_l)
  float*  u_buf   = (float*)(ws + 5242880);    // 16384 x 64 f32 (overlaps idx_l)
  int*    idx_fps = (int*)(ws + 9437184);      // 16384 x 32
  int*    idx1_i  = (int*)(ws + 11534336);     // 16384 x 14
  float*  h1max   = (float*)(ws + 12451840);   // 16384 x 32
  float*  s_buf   = (float*)(ws + 14548992);   // 16384 x 32
  float*  v_buf   = (float*)(ws + 16646144);   // 16384 x 32
  float*  h3max   = (float*)(ws + 18743296);   // 16384 x 64

  hipMemsetAsync(d_ws, 0, 656640, stream);     // zero stat accumulators

  xpose_kernel   <<<dim3(256),  dim3(256), 0, stream>>>(x, xT, sqx);
  ppose_kernel   <<<dim3(64),   dim3(192), 0, stream>>>(pos, posT);
  knn_pos_kernel <<<dim3(2048), dim3(512), 0, stream>>>(pos, posT, idx_l, idx1_i, out_idx1);
  knn_feat_kernel<<<dim3(4096), dim3(256), 0, stream>>>(x, xT, sqx, idx1_i, out_idx1);
  fps_kernel     <<<dim3(4096), dim3(256), 0, stream>>>(pos, idx_l, idx_fps);
  // idx_l dead from here; t/u reuse its space
  sv_kernel      <<<dim3(2048), dim3(256), 0, stream>>>(x, W1, s_buf, v_buf);
  h1stats_kernel <<<dim3(2048), dim3(256), 0, stream>>>(s_buf, v_buf, idx1_i, slotsH1, h1max);
  finalize_stats_kernel<<<dim3(1), dim3(64), 0, stream>>>(slotsH1, 32, 229376.0, g1, b1, scsh1);
  tu_kernel      <<<dim3(4096), dim3(256), 0, stream>>>(h1max, scsh1, W2, t_buf, u_buf);
  h2stats_kernel <<<dim3(2048), dim3(256), 0, stream>>>(t_buf, u_buf, idx_fps, slotsH2);
  finalize_stats_kernel<<<dim3(1), dim3(64), 0, stream>>>(slotsH2, 64, 524288.0, g2, b2, scsh2);
  h3_kernel      <<<dim3(2048), dim3(256), 0, stream>>>(t_buf, u_buf, idx_fps, W3, scsh2, slotsH3, h3max);
  finalize_stats_kernel<<<dim3(1), dim3(64), 0, stream>>>(slotsH3, 64, 524288.0, g3, b3, scsh3);
  out_kernel     <<<dim3(4096), dim3(256), 0, stream>>>(h3max, scsh3, out);
}

// Round 11
// 666.142 us; speedup vs baseline: 1.1001x; 1.0847x over previous
//
#include <hip/hip_runtime.h>

#define NPTS 4096
#define BNROWS 16384

__device__ __forceinline__ float lrelu(float h) { return h > 0.f ? h : 0.2f * h; }

// wave-local LDS fence: orders this wave's LDS ops (lockstep wave64 + lgkmcnt)
#define WSYNC asm volatile("s_waitcnt lgkmcnt(0)" ::: "memory")

__device__ __forceinline__ float rfl(float v) {
  return __int_as_float(__builtin_amdgcn_readfirstlane(__float_as_int(v)));
}

__device__ __forceinline__ unsigned long long shflx64(unsigned long long v, int m) {
  int lo = __shfl_xor((int)(unsigned int)(v & 0xffffffffull), m, 64);
  int hi = __shfl_xor((int)(unsigned int)(v >> 32), m, 64);
  return ((unsigned long long)(unsigned int)hi << 32) | (unsigned int)lo;
}

// ================= K0: per-row squared norms of x ==================
__global__ __launch_bounds__(256) void norms_kernel(
    const float* __restrict__ x, float* __restrict__ sqx)
{
  int r = blockIdx.x * 256 + threadIdx.x;
  const float4* xp = (const float4*)(x + (size_t)r * 16);
  float4 a0 = xp[0], a1 = xp[1], a2 = xp[2], a3 = xp[3];
  float s = a0.x*a0.x + a0.y*a0.y + a0.z*a0.z + a0.w*a0.w
          + a1.x*a1.x + a1.y*a1.y + a1.z*a1.z + a1.w*a1.w
          + a2.x*a2.x + a2.y*a2.y + a2.z*a2.z + a2.w*a2.w
          + a3.x*a3.x + a3.y*a3.y + a3.z*a3.z + a3.w*a3.w;
  sqx[r] = s;
}

// ================= K1: pos 128-NN (sorted) + idx_pos, v3 ==================
// 8 waves/block, one row per wave. AoS distance pass (known-good), candidate
// ids compacted to LDS (u32), fp64 rerank into 8 packed u64 regs/lane, then
// REGISTER bitonic-512 (shfl_xor for j<64, reg swaps for j>=64). No LDS sort,
// no per-phase lgkmcnt drains.
__global__ __launch_bounds__(512) void knn_pos_kernel(
    const float* __restrict__ pos, int* __restrict__ idx_l,
    int* __restrict__ idx1_i, float* __restrict__ idx1_f)
{
  __shared__ int cand[8][512];
  __shared__ unsigned int cCnt[8];
  int tid = threadIdx.x;
  int w = tid >> 6, lane = tid & 63;
  int r = blockIdx.x * 8 + w;
  int b = r >> 12, n = r & 4095;
  const float* pb = pos + (size_t)b * NPTS * 3;
  float cx = pb[n*3+0], cy = pb[n*3+1], cz = pb[n*3+2];
  if (lane == 0) cCnt[w] = 0u;
  WSYNC;

  unsigned int qp[32];
  int m1 = 65536, m2 = 65536, m3 = 65536;
  #pragma unroll
  for (int t = 0; t < 32; ++t) {
    unsigned int wq = 0u;
    #pragma unroll
    for (int h = 0; h < 2; ++h) {
      int j = (2*t + h) * 64 + lane;
      float dx = cx - pb[j*3+0], dy = cy - pb[j*3+1], dz = cz - pb[j*3+2];
      float d2 = dx*dx + dy*dy + dz*dz;
      int q = (int)(d2 * 1000.0f);
      q = q < 0 ? 0 : (q > 65535 ? 65535 : q);
      wq |= ((unsigned int)q) << (16*h);
      int nm1 = min(m1, q);
      int nm2 = min(m2, max(m1, q));
      int nm3 = min(m3, max(m2, q));
      m1 = nm1; m2 = nm2; m3 = nm3;
    }
    qp[t] = wq;
  }
  // smallest qt with >=43 lanes having 3rd-min <= qt  => >=129 pts <= qt
  int lo = 0, hi = 65535;
  #pragma unroll
  for (int it = 0; it < 16; ++it) {
    int mid = (lo + hi) >> 1;
    int cnt = __popcll(__ballot(m3 <= mid));
    if (cnt >= 43) hi = mid; else lo = mid + 1;
  }
  unsigned int qt = (unsigned int)lo + 2u;   // +2 bucket slack (fp32 vs fp64)

  // candidate compaction (ids only)
  #pragma unroll
  for (int t = 0; t < 32; ++t) {
    unsigned int wq = qp[t];
    unsigned int q0 = wq & 0xffffu, q1 = wq >> 16;
    if (q0 <= qt) { unsigned int p = atomicAdd(&cCnt[w], 1u); if (p < 512u) cand[w][p] = (2*t)*64 + lane; }
    if (q1 <= qt) { unsigned int p = atomicAdd(&cCnt[w], 1u); if (p < 512u) cand[w][p] = (2*t+1)*64 + lane; }
  }
  WSYNC;
  unsigned int nc = cCnt[w]; if (nc > 512u) nc = 512u;

  // exact fp64 rerank into 8 packed (keybits|idx) registers per lane
  double cxd = (double)cx, cyd = (double)cy, czd = (double)cz;
  unsigned long long key[8];
  #pragma unroll
  for (int t = 0; t < 8; ++t) {
    int c = (t << 6) | lane;
    unsigned long long kk = ~0ull;
    if (c < (int)nc) {
      int id = cand[w][c];
      double dx = cxd - (double)pb[id*3+0];
      double dy = cyd - (double)pb[id*3+1];
      double dz = czd - (double)pb[id*3+2];
      double d2 = dx*dx + dy*dy + dz*dz;
      unsigned long long bits = (unsigned long long)__double_as_longlong(d2);
      kk = (bits & ~0xFFFull) | (unsigned long long)(unsigned int)id;
    }
    key[t] = kk;
  }

  // register bitonic-512, ascending; element i = (t<<6)|lane
  #pragma unroll
  for (int kk2 = 1; kk2 <= 9; ++kk2) {
    const int k = 1 << kk2;
    #pragma unroll
    for (int jj = kk2 - 1; jj >= 0; --jj) {
      const int j = 1 << jj;
      if (j >= 64) {
        const int jt = j >> 6;
        #pragma unroll
        for (int t = 0; t < 8; ++t) {
          const int tp = t ^ jt;
          if (tp > t) {
            const bool up = (((t << 6) & k) == 0);
            unsigned long long a = key[t], bq = key[tp];
            if ((a > bq) == up) { key[t] = bq; key[tp] = a; }
          }
        }
      } else {
        #pragma unroll
        for (int t = 0; t < 8; ++t) {
          unsigned long long p = shflx64(key[t], j);
          bool up = ((((t << 6) | lane) & k) == 0);
          bool lower = ((lane & j) == 0);
          unsigned long long mn = (key[t] < p) ? key[t] : p;
          unsigned long long mx = (key[t] < p) ? p : key[t];
          key[t] = (lower == up) ? mn : mx;
        }
      }
    }
  }

  idx_l[(size_t)r * 128 + lane]      = (int)(key[0] & 0xFFFull);
  idx_l[(size_t)r * 128 + lane + 64] = (int)(key[1] & 0xFFFull);
  if (lane >= 1 && lane < 7) {
    int v = (int)(key[0] & 0xFFFull);
    idx1_i[r * 14 + 8 + (lane - 1)] = v;
    idx1_f[r * 14 + 8 + (lane - 1)] = (float)v;
  }
}

// ================= K2: feature 8-NN (excl self), v3 (R8 known-good) ==========
__global__ __launch_bounds__(256) void knn_feat_kernel(
    const float* __restrict__ x, const float* __restrict__ sqx,
    int* __restrict__ idx1_i, float* __restrict__ idx1_f)
{
  __shared__ float lmin[4][256];
  __shared__ int cand[4][192];
  __shared__ unsigned int cCnt[4];
  __shared__ float qtS[4];
  __shared__ float ctrf[4][16];
  int tid = threadIdx.x;
  int w = tid >> 6, lane = tid & 63;
  int rbase = blockIdx.x * 4;
  int b = rbase >> 12;
  const float* xb = x + (size_t)b * NPTS * 16;
  const float* sqb = sqx + b * NPTS;

  if (tid < 64) {
    int rr = tid >> 4, c = tid & 15;
    ctrf[rr][c] = xb[(size_t)((rbase + rr) & 4095) * 16 + c];   // batch-local row
  }
  if (tid < 4) cCnt[tid] = 0u;
  __syncthreads();

  // centers: cm = -2*ctr, c2 = |ctr|^2 (wave-uniform)
  float cm[4][16], c2[4];
  #pragma unroll
  for (int rr = 0; rr < 4; ++rr) {
    float s = 0.f;
    #pragma unroll
    for (int c = 0; c < 16; ++c) {
      float v = ctrf[rr][c];
      cm[rr][c] = rfl(-2.0f * v);
      s = fmaf(v, v, s);
    }
    c2[rr] = rfl(s);
  }

  // distance pass: fp32 Gram keys in registers
  float key[4][16];
  float fk[4] = {3.4e38f, 3.4e38f, 3.4e38f, 3.4e38f};
  #pragma unroll
  for (int pt = 0; pt < 16; ++pt) {
    int j = tid + 256 * pt;
    const float4* xj = (const float4*)(xb + (size_t)j * 16);
    float4 a0 = xj[0], a1 = xj[1], a2 = xj[2], a3 = xj[3];
    float sqj = sqb[j];
    float va[16] = {a0.x,a0.y,a0.z,a0.w, a1.x,a1.y,a1.z,a1.w,
                    a2.x,a2.y,a2.z,a2.w, a3.x,a3.y,a3.z,a3.w};
    #pragma unroll
    for (int rr = 0; rr < 4; ++rr) {
      float acc = sqj + c2[rr];
      #pragma unroll
      for (int c = 0; c < 16; ++c) acc = fmaf(va[c], cm[rr][c], acc);
      key[rr][pt] = acc;
      fk[rr] = fminf(fk[rr], acc);
    }
  }
  #pragma unroll
  for (int rr = 0; rr < 4; ++rr) lmin[rr][tid] = fk[rr];
  __syncthreads();

  // wave w: threshold for row w = 10th smallest of 256 thread-minima
  {
    float lv0 = lmin[w][lane], lv1 = lmin[w][lane + 64];
    float lv2 = lmin[w][lane + 128], lv3 = lmin[w][lane + 192];
    unsigned int lo = 0u, hi = 0x7F800000u;
    for (int it = 0; it < 31; ++it) {
      unsigned int mid = (lo + hi) >> 1;
      float midf = __uint_as_float(mid);
      int cnt = __popcll(__ballot(lv0 <= midf)) + __popcll(__ballot(lv1 <= midf))
              + __popcll(__ballot(lv2 <= midf)) + __popcll(__ballot(lv3 <= midf));
      if (cnt >= 10) hi = mid; else lo = mid + 1;
    }
    // slack covers fp32-Gram vs fp64-direct ordering error (<~2e-4)
    if (lane == 0) qtS[w] = __uint_as_float(hi) * 1.0002f + 1e-3f;
  }
  __syncthreads();

  // compaction
  {
    float q0 = qtS[0], q1 = qtS[1], q2 = qtS[2], q3 = qtS[3];
    #pragma unroll
    for (int pt = 0; pt < 16; ++pt) {
      int j = tid + 256 * pt;
      if (key[0][pt] <= q0) { unsigned int p = atomicAdd(&cCnt[0], 1u); if (p < 192u) cand[0][p] = j; }
      if (key[1][pt] <= q1) { unsigned int p = atomicAdd(&cCnt[1], 1u); if (p < 192u) cand[1][p] = j; }
      if (key[2][pt] <= q2) { unsigned int p = atomicAdd(&cCnt[2], 1u); if (p < 192u) cand[2][p] = j; }
      if (key[3][pt] <= q3) { unsigned int p = atomicAdd(&cCnt[3], 1u); if (p < 192u) cand[3][p] = j; }
    }
  }
  __syncthreads();

  // wave w: fp64 rerank of row w's candidates + 9 sorted min-extractions
  {
    int nc = (int)cCnt[w]; if (nc > 192) nc = 192;
    double key64[3]; int kid[3];
    #pragma unroll
    for (int s = 0; s < 3; ++s) {
      int c = lane + 64*s;
      if (c < nc) {
        int id = cand[w][c];
        const float4* xp = (const float4*)(xb + (size_t)id * 16);
        float4 q0 = xp[0], q1 = xp[1], q2 = xp[2], q3 = xp[3];
        float xv[16] = {q0.x,q0.y,q0.z,q0.w, q1.x,q1.y,q1.z,q1.w,
                        q2.x,q2.y,q2.z,q2.w, q3.x,q3.y,q3.z,q3.w};
        double acc = 0.0;
        #pragma unroll
        for (int c2i = 0; c2i < 16; ++c2i) { double d = (double)ctrf[w][c2i] - (double)xv[c2i]; acc += d * d; }
        key64[s] = acc; kid[s] = id;
      } else { key64[s] = 1e300; kid[s] = 0x7fffffff; }
    }
    int row = rbase + w;
    for (int it = 0; it < 9; ++it) {
      double bk = key64[0]; int bi = kid[0], bs = 0;
      if (key64[1] < bk || (key64[1] == bk && kid[1] < bi)) { bk = key64[1]; bi = kid[1]; bs = 1; }
      if (key64[2] < bk || (key64[2] == bk && kid[2] < bi)) { bk = key64[2]; bi = kid[2]; bs = 2; }
      double rk = bk; int ri = bi;
      #pragma unroll
      for (int off = 32; off > 0; off >>= 1) {
        double ok = __shfl_xor(rk, off, 64);
        int oi = __shfl_xor(ri, off, 64);
        if (ok < rk || (ok == rk && oi < ri)) { rk = ok; ri = oi; }
      }
      if (it > 0 && lane == 0) {
        idx1_i[row * 14 + it - 1] = ri;
        idx1_f[row * 14 + it - 1] = (float)ri;
      }
      if (bi == ri) key64[bs] = 1e300;
    }
  }
}

// ================= K3: FPS (replicates reference's batch-0 gather) =============
__global__ __launch_bounds__(256) void fps_kernel(
    const float* __restrict__ pos, const int* __restrict__ idx_l, int* __restrict__ idx_fps)
{
  int wave = threadIdx.x >> 6, lane = threadIdx.x & 63;
  int r = blockIdx.x * 4 + wave;
  const int* il = idx_l + (size_t)r * 128;
  int gi0 = il[lane], gi1 = il[lane + 64];
  double x0 = (double)pos[gi0*3+0], y0 = (double)pos[gi0*3+1], z0 = (double)pos[gi0*3+2];
  double x1 = (double)pos[gi1*3+0], y1 = (double)pos[gi1*3+1], z1 = (double)pos[gi1*3+2];
  double d0 = 1e10, d1 = 1e10;
  int far = 0;
  int* outp = idx_fps + (size_t)r * 32;
  for (int i = 0; i < 32; ++i) {
    int ownerLane = far & 63;
    int sel = far >> 6;
    int gsel = sel ? gi1 : gi0;
    int gout = __shfl(gsel, ownerLane, 64);
    if (lane == 0) outp[i] = gout;
    double cx = __shfl(sel ? x1 : x0, ownerLane, 64);
    double cy = __shfl(sel ? y1 : y0, ownerLane, 64);
    double cz = __shfl(sel ? z1 : z0, ownerLane, 64);
    double t0 = (x0-cx)*(x0-cx) + (y0-cy)*(y0-cy) + (z0-cz)*(z0-cz);
    double t1 = (x1-cx)*(x1-cx) + (y1-cy)*(y1-cy) + (z1-cz)*(z1-cz);
    d0 = fmin(d0, t0); d1 = fmin(d1, t1);
    double v; int p;
    if (d1 > d0) { v = d1; p = lane + 64; } else { v = d0; p = lane; }
    for (int off = 32; off > 0; off >>= 1) {
      double ov = __shfl_xor(v, off, 64);
      int op = __shfl_xor(p, off, 64);
      if (ov > v || (ov == v && op < p)) { v = ov; p = op; }
    }
    far = p;
  }
}

// ========== K4a: s[gr][o] = x[gr]·W1a[o], v[gr][o] = x[gr]·(W1b-W1a)[o] ==========
__global__ __launch_bounds__(256) void sv_kernel(
    const float* __restrict__ x, const float* __restrict__ W1,
    float* __restrict__ s, float* __restrict__ v)
{
  __shared__ float xs[8][16];
  __shared__ float w1t[512], w1dt[512];
  int tid = threadIdx.x;
  int rbase = blockIdx.x * 8;
  for (int i = tid; i < 512; i += 256) {
    int c = i >> 5, o = i & 31;
    float a = W1[o * 32 + c], bb = W1[o * 32 + 16 + c];
    w1t[i] = a; w1dt[i] = bb - a;
  }
  if (tid < 128) { int rr = tid >> 4, c = tid & 15; xs[rr][c] = x[(size_t)(rbase + rr) * 16 + c]; }
  __syncthreads();
  int rr = tid >> 5, o = tid & 31;
  float sa = 0.f, va = 0.f;
  #pragma unroll
  for (int c = 0; c < 16; ++c) {
    float xv = xs[rr][c];
    sa = fmaf(xv, w1t[c * 32 + o], sa);
    va = fmaf(xv, w1dt[c * 32 + o], va);
  }
  int r = rbase + rr;
  s[(size_t)r * 32 + o] = sa;
  v[(size_t)r * 32 + o] = va;
}

// ========== K4b: h1max + h1 stats via gathered s + v ==========
__global__ __launch_bounds__(256) void h1stats_kernel(
    const float* __restrict__ s, const float* __restrict__ v, const int* __restrict__ idx1_i,
    double* __restrict__ slotsH1, float* __restrict__ h1max)
{
  __shared__ int sidx[8][14];
  __shared__ float sred[256], sred2[256];
  int tid = threadIdx.x;
  int rr = tid >> 5, o = tid & 31;
  int rbase = blockIdx.x * 8;
  if (tid < 112) { int q = tid / 14, k = tid % 14; sidx[q][k] = idx1_i[(rbase + q) * 14 + k]; }
  __syncthreads();
  int r = rbase + rr;
  int broff = r & ~4095;
  float vv = v[(size_t)r * 32 + o];
  float m = -3.4e38f, ls = 0.f, lss = 0.f;
  #pragma unroll
  for (int k = 0; k < 14; ++k) {
    int j = sidx[rr][k];
    float val = s[(size_t)(broff + j) * 32 + o] + vv;
    m = fmaxf(m, val);
    ls += val; lss += val * val;
  }
  h1max[(size_t)r * 32 + o] = m;
  sred[tid] = ls; sred2[tid] = lss;
  __syncthreads();
  if (tid < 32) {
    float s2 = 0.f, ss = 0.f;
    #pragma unroll
    for (int j = 0; j < 8; ++j) { s2 += sred[j * 32 + tid]; ss += sred2[j * 32 + tid]; }
    int slot = blockIdx.x & 255;
    atomicAdd(&slotsH1[slot * 64 + tid], (double)s2);
    atomicAdd(&slotsH1[slot * 64 + 32 + tid], (double)ss);
  }
}

// ---------------- stats finalize: scsh = [sc(C), sh(C)] ----------------
__global__ void finalize_stats_kernel(const double* __restrict__ slots, int C, double cnt,
    const float* __restrict__ g, const float* __restrict__ bta, float* __restrict__ scsh)
{
  int o = threadIdx.x;
  if (o < C) {
    double s = 0.0, ss = 0.0;
    for (int slot = 0; slot < 256; ++slot) { s += slots[slot * 2 * C + o]; ss += slots[slot * 2 * C + C + o]; }
    double mu = s / cnt;
    double var = ss / cnt - mu * mu;
    double rs = 1.0 / sqrt(var + 1e-5);
    float sc = (float)rs * g[o];
    float sh = bta[o] - (float)mu * sc;
    scsh[o] = sc;
    scsh[C + o] = sh;
  }
}

// ========== K5a: f1 = lrelu(affine(h1max)); t = f1·W2a, u = f1·(W2b-W2a) ==========
__global__ __launch_bounds__(256) void tu_kernel(
    const float* __restrict__ h1max, const float* __restrict__ scsh1, const float* __restrict__ W2,
    float* __restrict__ t, float* __restrict__ u)
{
  __shared__ float f1s[4][32];
  __shared__ float w2t[2048], w2dt[2048];
  int tid = threadIdx.x;
  int rbase = blockIdx.x * 4;
  for (int i = tid; i < 2048; i += 256) {
    int c = i >> 6, o = i & 63;
    float a = W2[o * 64 + c], bb = W2[o * 64 + 32 + c];
    w2t[i] = a; w2dt[i] = bb - a;
  }
  if (tid < 128) {
    int rr = tid >> 5, c = tid & 31;
    f1s[rr][c] = lrelu(h1max[(size_t)(rbase + rr) * 32 + c] * scsh1[c] + scsh1[32 + c]);
  }
  __syncthreads();
  int rr = tid >> 6, o = tid & 63;
  float ta = 0.f, ua = 0.f;
  #pragma unroll
  for (int c = 0; c < 32; ++c) {
    float fv = f1s[rr][c];
    ta = fmaf(fv, w2t[c * 64 + o], ta);
    ua = fmaf(fv, w2dt[c * 64 + o], ua);
  }
  int r = rbase + rr;
  t[(size_t)r * 64 + o] = ta;
  u[(size_t)r * 64 + o] = ua;
}

// ========== K5b: h2 stats via gathered t + u ==========
__global__ __launch_bounds__(256) void h2stats_kernel(
    const float* __restrict__ t, const float* __restrict__ u, const int* __restrict__ idx_fps,
    double* __restrict__ slotsH2)
{
  __shared__ int nids[8][32];
  __shared__ float sred[256], sred2[256];
  int tid = threadIdx.x;
  int o = tid & 63, wv = tid >> 6;
  int rbase = blockIdx.x * 8;
  { int q = tid >> 5, k = tid & 31; nids[q][k] = idx_fps[(rbase + q) * 32 + k]; }
  __syncthreads();
  float ls = 0.f, lss = 0.f;
  for (int rr = 0; rr < 8; ++rr) {
    int r = rbase + rr;
    int broff = r & ~4095;
    float uo = u[(size_t)r * 64 + o];
    #pragma unroll
    for (int i = 0; i < 8; ++i) {
      int k = wv + 4 * i;
      float val = t[(size_t)(broff + nids[rr][k]) * 64 + o] + uo;
      ls += val; lss += val * val;
    }
  }
  sred[tid] = ls; sred2[tid] = lss;
  __syncthreads();
  if (tid < 64) {
    float s2 = sred[tid] + sred[tid + 64] + sred[tid + 128] + sred[tid + 192];
    float ss = sred2[tid] + sred2[tid + 64] + sred2[tid + 128] + sred2[tid + 192];
    int slot = blockIdx.x & 255;
    atomicAdd(&slotsH2[slot * 128 + tid], (double)s2);
    atomicAdd(&slotsH2[slot * 128 + 64 + tid], (double)ss);
  }
}

// ========== K6: h3 = lrelu(affine(t[nid]+u))·W3ᵀ, stats + channel max ==========
#define ROWS3 8
__global__ __launch_bounds__(256, 4) void h3_kernel(
    const float* __restrict__ t, const float* __restrict__ u, const int* __restrict__ idx_fps,
    const float* __restrict__ W3, const float* __restrict__ scsh2,
    double* __restrict__ slotsH3, float* __restrict__ h3max)
{
  __shared__ float h2lds[2048];
  __shared__ float wmax[256];
  __shared__ float sred[256], sred2[256];
  __shared__ int nids[ROWS3][32];
  int tid = threadIdx.x;
  int o = tid & 63, wv = tid >> 6;
  float4 w3r[16];
  const float4* w3p = (const float4*)(W3 + o * 64);
  #pragma unroll
  for (int j = 0; j < 16; ++j) w3r[j] = w3p[j];
  float sc2o = scsh2[o], sh2o = scsh2[64 + o];
  int rbase = blockIdx.x * ROWS3;
  { int q = tid >> 5, k = tid & 31; nids[q][k] = idx_fps[(rbase + q) * 32 + k]; }
  float ls = 0.f, lss = 0.f;
  __syncthreads();
  for (int rr = 0; rr < ROWS3; ++rr) {
    int r = rbase + rr;
    int broff = r & ~4095;
    float uo = u[(size_t)r * 64 + o];
    #pragma unroll
    for (int i = 0; i < 8; ++i) {
      int k = wv + 4 * i;
      float val = t[(size_t)(broff + nids[rr][k]) * 64 + o] + uo;
      h2lds[k * 64 + o] = lrelu(val * sc2o + sh2o);
    }
    __syncthreads();
    float kmax = -3.4e38f;
    #pragma unroll
    for (int i = 0; i < 8; ++i) {
      int k = wv + 4 * i;
      const float4* hp = (const float4*)(h2lds + k * 64);
      float acc = 0.f;
      #pragma unroll
      for (int j = 0; j < 16; ++j) {
        float4 h = hp[j];
        acc = fmaf(h.x, w3r[j].x, acc); acc = fmaf(h.y, w3r[j].y, acc);
        acc = fmaf(h.z, w3r[j].z, acc); acc = fmaf(h.w, w3r[j].w, acc);
      }
      ls += acc; lss += acc * acc;
      kmax = fmaxf(kmax, acc);
    }
    wmax[tid] = kmax;
    __syncthreads();
    if (tid < 64) {
      float m = fmaxf(fmaxf(wmax[tid], wmax[64 + tid]), fmaxf(wmax[128 + tid], wmax[192 + tid]));
      h3max[(size_t)r * 64 + tid] = m;
    }
  }
  sred[tid] = ls; sred2[tid] = lss;
  __syncthreads();
  if (tid < 64) {
    float s2 = sred[tid] + sred[tid + 64] + sred[tid + 128] + sred[tid + 192];
    float ss = sred2[tid] + sred2[tid + 64] + sred2[tid + 128] + sred2[tid + 192];
    int slot = blockIdx.x & 255;
    atomicAdd(&slotsH3[slot * 128 + tid], (double)s2);
    atomicAdd(&slotsH3[slot * 128 + 64 + tid], (double)ss);
  }
}

// ---------------- K10: out = lrelu(affine(h3max)) ----------------
__global__ void out_kernel(const float* __restrict__ h3max, const float* __restrict__ scsh3,
                           float* __restrict__ out)
{
  int i = blockIdx.x * 256 + threadIdx.x;
  int o = i & 63;
  out[i] = lrelu(h3max[i] * scsh3[o] + scsh3[64 + o]);
}

extern "C" void kernel_launch(void* const* d_in, const int* in_sizes, int n_in,
                              void* d_out, int out_size, void* d_ws, size_t ws_size,
                              hipStream_t stream) {
  (void)in_sizes; (void)n_in; (void)out_size; (void)ws_size;
  const float* x   = (const float*)d_in[0];
  const float* pos = (const float*)d_in[1];
  const float* W1  = (const float*)d_in[2];
  const float* g1  = (const float*)d_in[3];
  const float* b1  = (const float*)d_in[4];
  const float* W2  = (const float*)d_in[5];
  const float* g2  = (const float*)d_in[6];
  const float* b2  = (const float*)d_in[7];
  const float* W3  = (const float*)d_in[8];
  const float* g3  = (const float*)d_in[9];
  const float* b3  = (const float*)d_in[10];

  float* out      = (float*)d_out;             // (4,4096,64) f32
  float* out_idx1 = out + 1048576;             // (4,4096,14) written as float(idx)

  char* ws = (char*)d_ws;
  double* slotsH1 = (double*)(ws + 0);         // 256 x 64 double
  double* slotsH2 = (double*)(ws + 131072);    // 256 x 128 double
  double* slotsH3 = (double*)(ws + 393216);    // 256 x 128 double
  float*  scsh1   = (float*)(ws + 655360);     // 64 f
  float*  scsh2   = (float*)(ws + 655616);     // 128 f
  float*  scsh3   = (float*)(ws + 656128);     // 128 f
  float*  sqx     = (float*)(ws + 786432);     // 16384 f
  int*    idx_l   = (int*)(ws + 1048576);      // 16384 x 128 (freed after fps)
  float*  t_buf   = (float*)(ws + 1048576);    // 16384 x 64 f32 (overlaps idx_l)
  float*  u_buf   = (float*)(ws + 5242880);    // 16384 x 64 f32 (overlaps idx_l)
  int*    idx_fps = (int*)(ws + 9437184);      // 16384 x 32
  int*    idx1_i  = (int*)(ws + 11534336);     // 16384 x 14
  float*  h1max   = (float*)(ws + 12451840);   // 16384 x 32
  float*  s_buf   = (float*)(ws + 14548992);   // 16384 x 32
  float*  v_buf   = (float*)(ws + 16646144);   // 16384 x 32
  float*  h3max   = (float*)(ws + 18743296);   // 16384 x 64

  hipMemsetAsync(d_ws, 0, 656640, stream);     // zero stat accumulators

  norms_kernel   <<<dim3(64),   dim3(256), 0, stream>>>(x, sqx);
  knn_pos_kernel <<<dim3(2048), dim3(512), 0, stream>>>(pos, idx_l, idx1_i, out_idx1);
  knn_feat_kernel<<<dim3(4096), dim3(256), 0, stream>>>(x, sqx, idx1_i, out_idx1);
  fps_kernel     <<<dim3(4096), dim3(256), 0, stream>>>(pos, idx_l, idx_fps);
  // idx_l dead from here; t/u reuse its space
  sv_kernel      <<<dim3(2048), dim3(256), 0, stream>>>(x, W1, s_buf, v_buf);
  h1stats_kernel <<<dim3(2048), dim3(256), 0, stream>>>(s_buf, v_buf, idx1_i, slotsH1, h1max);
  finalize_stats_kernel<<<dim3(1), dim3(64), 0, stream>>>(slotsH1, 32, 229376.0, g1, b1, scsh1);
  tu_kernel      <<<dim3(4096), dim3(256), 0, stream>>>(h1max, scsh1, W2, t_buf, u_buf);
  h2stats_kernel <<<dim3(2048), dim3(256), 0, stream>>>(t_buf, u_buf, idx_fps, slotsH2);
  finalize_stats_kernel<<<dim3(1), dim3(64), 0, stream>>>(slotsH2, 64, 524288.0, g2, b2, scsh2);
  h3_kernel      <<<dim3(2048), dim3(256), 0, stream>>>(t_buf, u_buf, idx_fps, W3, scsh2, slotsH3, h3max);
  finalize_stats_kernel<<<dim3(1), dim3(64), 0, stream>>>(slotsH3, 64, 524288.0, g3, b3, scsh3);
  out_kernel     <<<dim3(4096), dim3(256), 0, stream>>>(h3max, scsh3, out);
}